// Round 4
// baseline (180.483 us; speedup 1.0000x reference)
//
#include <hip/hip_runtime.h>

// MaskPatchClassificationHead — B=4, P=256, F=512
// Single fused kernel, 256 blocks x 512 threads (1 block/CU, all co-resident):
//   phase 1: fc partial GEMM (K-split 2) + label sigs        [round-3 fc_sig]
//   phase 2: score partial GEMM (h h^T, K-split 4)           [round-3 score_gemm]
//   phase 3: softmax/KL loss + atomicAdd + out               [round-3 loss]
// Software grid barriers: per-phase flag array, exact-match magic per slot
// (robust to 0xAA poison / zeros / garbage init), agent-scope atomics +
// threadfence for cross-XCD visibility, bounded spin (no-hang escape).

#define INV_TAU (1.0f / 0.07f)
#define EPSC 1e-5f

constexpr int Bz = 4;
constexpr int Pn = 256;
constexpr int Fdim = 512;
constexpr int Mrows = Bz * Pn;                       // 1024
constexpr size_t HP_STRIDE = (size_t)Mrows * Fdim;   // per fc K-half partial
constexpr size_t SP_STRIDE = (size_t)Bz * Pn * Pn;   // per score K-quarter partial

__device__ __forceinline__ float wave_sum(float v) {
  #pragma unroll
  for (int o = 32; o > 0; o >>= 1) v += __shfl_down(v, o, 64);
  return v;
}
__device__ __forceinline__ float wave_max(float v) {
  #pragma unroll
  for (int o = 32; o > 0; o >>= 1) v = fmaxf(v, __shfl_down(v, o, 64));
  return v;
}
__device__ __forceinline__ unsigned long long mix64(unsigned long long z) {
  z ^= z >> 33; z *= 0xff51afd7ed558ccdULL;
  z ^= z >> 33; z *= 0xc4ceb9fe1a85ec53ULL;
  z ^= z >> 33; return z;
}

// Grid barrier: each block publishes `magic` into its own slot (overwrites
// whatever poison was there), then 256 threads each poll one slot for exact
// match. Release/acquire via agent-scope atomics; bounded spin avoids hangs.
__device__ __forceinline__ void grid_barrier(int* flags, int magic) {
  __syncthreads();
  if (threadIdx.x == 0) {
    __threadfence();  // release: all prior global writes visible device-wide
    __hip_atomic_store(flags + blockIdx.x, magic, __ATOMIC_RELEASE,
                       __HIP_MEMORY_SCOPE_AGENT);
  }
  if (threadIdx.x < 256) {
    int spins = 0;
    while (__hip_atomic_load(flags + threadIdx.x, __ATOMIC_ACQUIRE,
                             __HIP_MEMORY_SCOPE_AGENT) != magic) {
      if (++spins > (1 << 22)) break;  // escape hatch: wrong answer, not hang
      __builtin_amdgcn_s_sleep(2);
    }
  }
  __syncthreads();
}

__global__ __launch_bounds__(512) void fused_kernel(
    const float* __restrict__ A, const float* __restrict__ W,
    const float* __restrict__ labels, const float* __restrict__ bias,
    float* __restrict__ hp, float* __restrict__ Sp,
    ulonglong2* __restrict__ sig, float* __restrict__ acc,
    int* __restrict__ flags, float* __restrict__ out) {
  const int t = threadIdx.x;
  const int bid = blockIdx.x;
  __shared__ float ldsbuf[2 * 32 * 68];  // fc/score tiles; reused by loss
  float (*Ash)[68] = (float(*)[68])ldsbuf;
  float (*Bsh)[68] = (float(*)[68])(ldsbuf + 32 * 68);

  if (bid == 0 && t == 0)
    __hip_atomic_store(acc, 0.0f, __ATOMIC_RELAXED, __HIP_MEMORY_SCOPE_AGENT);

  // ===== phase 1a: label signatures (4 rows/block, one 64-lane group each)
  {
    const int g = t >> 6, lane = t & 63;
    if (g < 4) {
      const int row = bid * 4 + g;
      const uint4* l4 = (const uint4*)(labels + (size_t)row * Fdim);
      unsigned long long h1 = 0, h2 = 0;
      #pragma unroll
      for (int c = lane; c < Fdim / 4; c += 64) {
        uint4 w = l4[c];
        unsigned long long w01 = ((unsigned long long)w.y << 32) | w.x;
        unsigned long long w23 = ((unsigned long long)w.w << 32) | w.z;
        unsigned long long idx = (unsigned long long)c;
        h1 ^= mix64(w01 + idx * 0x9E3779B97F4A7C15ULL + 0x0123456789ABCDEFULL);
        h1 ^= mix64(w23 + idx * 0xC2B2AE3D27D4EB4FULL + 1ULL);
        h2 ^= mix64(w01 ^ (idx * 0x165667B19E3779F9ULL + 7ULL));
        h2 ^= mix64(w23 ^ (idx * 0x27D4EB2F165667C5ULL + 13ULL));
      }
      #pragma unroll
      for (int o = 32; o > 0; o >>= 1) {
        h1 ^= __shfl_down(h1, o, 64);
        h2 ^= __shfl_down(h2, o, 64);
      }
      if (lane == 0) { sig[row].x = h1; sig[row].y = h2; }
    }
  }

  // ===== phase 1b: fc partial GEMM. 64x64 tile, 2x4 micro, BK=32.
  // hp[z][m][n] = sum_{k in half z} A[m][k] W[n][k]
  {
    const int bx = bid & 15, by = (bid >> 4) & 7, bz = bid >> 7;
    const int m0 = bx * 64, n0 = by * 64;
    const int kbase = bz * 256;
    float* C = hp + (size_t)bz * HP_STRIDE;
    const int tx = t & 15, ty = t >> 4;
    const int r0 = t >> 3, c0 = (t & 7) << 2;
    float a2[2][4] = {};

    for (int kc = 0; kc < 256; kc += 32) {
      const float* Ap = A + (size_t)(m0 + r0) * Fdim + kbase + kc + c0;
      const float* Wp = W + (size_t)(n0 + r0) * Fdim + kbase + kc + c0;
      float4 av = *(const float4*)Ap;
      float4 bv = *(const float4*)Wp;
      __syncthreads();
      Ash[c0+0][r0] = av.x; Ash[c0+1][r0] = av.y; Ash[c0+2][r0] = av.z; Ash[c0+3][r0] = av.w;
      Bsh[c0+0][r0] = bv.x; Bsh[c0+1][r0] = bv.y; Bsh[c0+2][r0] = bv.z; Bsh[c0+3][r0] = bv.w;
      __syncthreads();
      #pragma unroll 8
      for (int k = 0; k < 32; ++k) {
        float2 aa = *(const float2*)&Ash[k][ty << 1];
        float4 bb = *(const float4*)&Bsh[k][tx << 2];
        a2[0][0] = fmaf(aa.x, bb.x, a2[0][0]); a2[0][1] = fmaf(aa.x, bb.y, a2[0][1]);
        a2[0][2] = fmaf(aa.x, bb.z, a2[0][2]); a2[0][3] = fmaf(aa.x, bb.w, a2[0][3]);
        a2[1][0] = fmaf(aa.y, bb.x, a2[1][0]); a2[1][1] = fmaf(aa.y, bb.y, a2[1][1]);
        a2[1][2] = fmaf(aa.y, bb.z, a2[1][2]); a2[1][3] = fmaf(aa.y, bb.w, a2[1][3]);
      }
    }
    #pragma unroll
    for (int i = 0; i < 2; ++i) {
      float4 o; o.x = a2[i][0]; o.y = a2[i][1]; o.z = a2[i][2]; o.w = a2[i][3];
      *(float4*)(C + (size_t)(m0 + (ty << 1) + i) * Fdim + n0 + (tx << 2)) = o;
    }
  }

  grid_barrier(flags, 0x5EC7A5E1);

  // ===== phase 2: score partial GEMM. Sp[kz][b][p][q], K-quarter kz of
  // h[b*256+m][o] = hp0 + hp1 + bias[o]. 64x64 tile, 2x4 micro.
  {
    const int x = bid & 3, y = (bid >> 2) & 3, z = bid >> 4;
    const int b = z >> 2, kz = z & 3;
    const int kbase = kz * 128;
    const int m0 = x * 64, n0 = y * 64;
    const float* h0 = hp;
    const float* h1 = hp + HP_STRIDE;
    float* C = Sp + (size_t)kz * SP_STRIDE + (size_t)b * Pn * Pn;
    const size_t rb = (size_t)b * Pn;
    const int tx = t & 15, ty = t >> 4;
    const int r0 = t >> 3, c0 = (t & 7) << 2;
    float a2[2][4] = {};

    for (int kc = 0; kc < 128; kc += 32) {
      const int ko = kbase + kc + c0;
      float4 bi = *(const float4*)(bias + ko);
      size_t aoff = (rb + m0 + r0) * Fdim + ko;
      size_t boff = (rb + n0 + r0) * Fdim + ko;
      float4 al = *(const float4*)(h0 + aoff);
      float4 ah = *(const float4*)(h1 + aoff);
      float4 bl = *(const float4*)(h0 + boff);
      float4 bh = *(const float4*)(h1 + boff);
      float4 av, bv;
      av.x = al.x + ah.x + bi.x; av.y = al.y + ah.y + bi.y;
      av.z = al.z + ah.z + bi.z; av.w = al.w + ah.w + bi.w;
      bv.x = bl.x + bh.x + bi.x; bv.y = bl.y + bh.y + bi.y;
      bv.z = bl.z + bh.z + bi.z; bv.w = bl.w + bh.w + bi.w;
      __syncthreads();
      Ash[c0+0][r0] = av.x; Ash[c0+1][r0] = av.y; Ash[c0+2][r0] = av.z; Ash[c0+3][r0] = av.w;
      Bsh[c0+0][r0] = bv.x; Bsh[c0+1][r0] = bv.y; Bsh[c0+2][r0] = bv.z; Bsh[c0+3][r0] = bv.w;
      __syncthreads();
      #pragma unroll 8
      for (int k = 0; k < 32; ++k) {
        float2 aa = *(const float2*)&Ash[k][ty << 1];
        float4 bb = *(const float4*)&Bsh[k][tx << 2];
        a2[0][0] = fmaf(aa.x, bb.x, a2[0][0]); a2[0][1] = fmaf(aa.x, bb.y, a2[0][1]);
        a2[0][2] = fmaf(aa.x, bb.z, a2[0][2]); a2[0][3] = fmaf(aa.x, bb.w, a2[0][3]);
        a2[1][0] = fmaf(aa.y, bb.x, a2[1][0]); a2[1][1] = fmaf(aa.y, bb.y, a2[1][1]);
        a2[1][2] = fmaf(aa.y, bb.z, a2[1][2]); a2[1][3] = fmaf(aa.y, bb.w, a2[1][3]);
      }
    }
    #pragma unroll
    for (int i = 0; i < 2; ++i) {
      float4 o; o.x = a2[i][0]; o.y = a2[i][1]; o.z = a2[i][2]; o.w = a2[i][3];
      *(float4*)(C + (size_t)(m0 + (ty << 1) + i) * Pn + n0 + (tx << 2)) = o;
    }
  }

  grid_barrier(flags + 256, 0x5EC7A5E2);

  // ===== phase 3: loss. Block = (b, 4 rows); threads 0..255 active (q).
  {
    const int b = bid >> 6, p0 = (bid & 63) * 4;
    const int q = t;
    const bool act = (t < 256);
    float* invn = ldsbuf;        // 256 floats (reuse of tile LDS)
    float* red  = ldsbuf + 256;  // 12 floats
    const float* S0 = Sp + (size_t)b * Pn * Pn;
    const float* S1 = S0 + SP_STRIDE;
    const float* S2 = S0 + 2 * SP_STRIDE;
    const float* S3 = S0 + 3 * SP_STRIDE;

    ulonglong2 sq; sq.x = 0; sq.y = 0;
    if (act) {
      const int d = q * 257;
      float Sqq = S0[d] + S1[d] + S2[d] + S3[d];
      invn[q] = 1.0f / fmaxf(sqrtf(Sqq), 1e-12f);
      sq = sig[(b << 8) + q];
    }
    __syncthreads();

    float lane_contrib = 0.0f;
    #pragma unroll
    for (int i = 0; i < 4; ++i) {
      const int p = p0 + i;
      float s = -1e30f;
      bool eq = false;
      if (act) {
        const int ro = p << 8;
        float Spq = S0[ro + q] + S1[ro + q] + S2[ro + q] + S3[ro + q];
        s = Spq * invn[p] * invn[q] * INV_TAU;
        ulonglong2 sp = sig[(b << 8) + p];
        if (q == p) eq = true;
        else if (sp.x == sq.x && sp.y == sq.y) {
          bool v = true;
          const float* lp = labels + (size_t)((b << 8) + p) * Fdim;
          const float* lq = labels + (size_t)((b << 8) + q) * Fdim;
          for (int j = 0; j < Fdim; ++j) v = v && (lp[j] == lq[j]);
          eq = v;
        }
      }
      float m = wave_max(s);
      if (act && (q & 63) == 0) red[q >> 6] = m;
      __syncthreads();
      m = fmaxf(fmaxf(red[0], red[1]), fmaxf(red[2], red[3]));

      float e = act ? expf(s - m) : 0.0f;
      float zc = wave_sum(e);
      float cc = wave_sum(eq ? 1.0f : 0.0f);
      if (act && (q & 63) == 0) { red[4 + (q >> 6)] = zc; red[8 + (q >> 6)] = cc; }
      __syncthreads();
      float z = red[4] + red[5] + red[6] + red[7];
      float n = red[8] + red[9] + red[10] + red[11];

      if (act) {
        float prob = fminf(fmaxf(e / z, EPSC), 1.0f - EPSC);
        if (eq) lane_contrib += (-logf(n) - logf(prob)) / n;
      }
      __syncthreads();
    }

    float c = wave_sum(lane_contrib);
    if (act && (t & 63) == 0) red[t >> 6] = c;
    __syncthreads();
    if (t == 0) atomicAdd(acc, red[0] + red[1] + red[2] + red[3]);
  }

  grid_barrier(flags + 512, 0x5EC7A5E3);
  if (bid == 0 && t == 0)
    out[0] = __hip_atomic_load(acc, __ATOMIC_RELAXED, __HIP_MEMORY_SCOPE_AGENT)
             * (1.0f / (float)(Bz * Pn));
}

extern "C" void kernel_launch(void* const* d_in, const int* in_sizes, int n_in,
                              void* d_out, int out_size, void* d_ws, size_t ws_size,
                              hipStream_t stream) {
  const float* inputs = (const float*)d_in[0];
  const float* labels = (const float*)d_in[1];
  const float* W      = (const float*)d_in[2];
  const float* bias   = (const float*)d_in[3];
  float* out = (float*)d_out;

  char* ws = (char*)d_ws;
  int*   flags = (int*)ws;                         // 768 ints (3 barriers x 256)
  float* acc   = (float*)(ws + 4096);              // 4 B
  float* hp    = (float*)(ws + 8192);              // 2 * 2 MB fc partials
  float* Sp    = (float*)(ws + 8192 + 2 * HP_STRIDE * 4);  // 4 * 1 MB score partials
  ulonglong2* sig = (ulonglong2*)(ws + 8192 + 2 * HP_STRIDE * 4 + 4 * SP_STRIDE * 4);

  fused_kernel<<<256, 512, 0, stream>>>(inputs, W, labels, bias,
                                        hp, Sp, sig, acc, flags, out);
}